// Round 12
// baseline (1497.557 us; speedup 1.0000x reference)
//
#include <hip/hip_runtime.h>

#define NPTS 16384
#define CF 64
#define KCORR 2048
#define TCAND 64          // candidates per LDS tile in top2

// ---------------------------------------------------------------------------
// fp32 arithmetic variants (bit-exact emulation targets)
// ---------------------------------------------------------------------------

// THIS ROUND'S weight-dot variant: 8-lane FMA vectorized reduction
// (gcc/clang -O3 -ffp-contract=fast -march=x86-64-v3 on a plain dot loop;
// also ATen Vectorized<float> AVX2 kernels). Lane j accumulates c == j mod 8
// with true FMA; final halving tree ((v0+v4)+(v2+v6))+((v1+v5)+(v3+v7)).
__device__ __forceinline__ float dot_avx2(const float* __restrict__ a,
                                          const float* __restrict__ b) {
#pragma clang fp contract(off)
    float v0 = 0.f, v1 = 0.f, v2 = 0.f, v3 = 0.f;
    float v4 = 0.f, v5 = 0.f, v6 = 0.f, v7 = 0.f;
    #pragma unroll
    for (int i = 0; i < CF; i += 8) {
        v0 = fmaf(a[i + 0], b[i + 0], v0);
        v1 = fmaf(a[i + 1], b[i + 1], v1);
        v2 = fmaf(a[i + 2], b[i + 2], v2);
        v3 = fmaf(a[i + 3], b[i + 3], v3);
        v4 = fmaf(a[i + 4], b[i + 4], v4);
        v5 = fmaf(a[i + 5], b[i + 5], v5);
        v6 = fmaf(a[i + 6], b[i + 6], v6);
        v7 = fmaf(a[i + 7], b[i + 7], v7);
    }
    float u0 = v0 + v4, u1 = v1 + v5, u2 = v2 + v6, u3 = v3 + v7;
    float t0 = u0 + u2, t1 = u1 + u3;
    return t0 + t1;
}

// numpy pairwise_sum (8 <= n <= 128, contiguous): 8 accumulators seeded from
// the first 8 products, stride-8, combine ((r0+r1)+(r2+r3))+((r4+r5)+(r6+r7)).
// Used only for qq/ss (selection -- robust).
__device__ __forceinline__ float row_sumsq(const float* __restrict__ x) {
#pragma clang fp contract(off)
    float r[8];
    #pragma unroll
    for (int j = 0; j < 8; ++j) r[j] = x[j] * x[j];
    #pragma unroll
    for (int i = 8; i < 64; i += 8) {
        #pragma unroll
        for (int j = 0; j < 8; ++j) { float p = x[i + j] * x[i + j]; r[j] = r[j] + p; }
    }
    return ((r[0] + r[1]) + (r[2] + r[3])) + ((r[4] + r[5]) + (r[6] + r[7]));
}

// OpenBLAS/Eigen sgemm microkernel accumulation: single accumulator,
// ascending k, fp32 FMA. Used for dist2 SELECTION (robust: top-2 gaps ~0.02).
__device__ __forceinline__ float dot_fma(const float* __restrict__ a,
                                         const float* __restrict__ b) {
    float acc = 0.0f;
    #pragma unroll
    for (int c = 0; c < CF; ++c) acc = fmaf(a[c], b[c], acc);
    return acc;
}

// ---------------------------------------------------------------------------
// prep: per-row sum of squares, numpy-pairwise fp32. One thread per row.
// ---------------------------------------------------------------------------
__global__ __launch_bounds__(256) void prep_kernel(
    const float* __restrict__ src_feats, const float* __restrict__ tgt_feats,
    float* __restrict__ qq_src, float* __restrict__ qq_tgt)
{
    int t = blockIdx.x * 256 + threadIdx.x;      // 0 .. 2*NPTS-1
    if (t >= 2 * NPTS) return;
    const float* f = (t < NPTS) ? src_feats : tgt_feats;
    float*      qq = (t < NPTS) ? qq_src    : qq_tgt;
    int n = (t < NPTS) ? t : t - NPTS;
    float x[CF];
    #pragma unroll
    for (int c = 0; c < CF; c += 4) {
        float4 v = *(const float4*)(f + (size_t)n * CF + c);
        x[c] = v.x; x[c+1] = v.y; x[c+2] = v.z; x[c+3] = v.w;
    }
    qq[n] = row_sumsq(x);
}

// ---------------------------------------------------------------------------
// top2: per query, scan a chunk of candidates, keep 2 smallest fp32 dist2:
// d2 = (qq - 2*dot_sgemm) + ss, each step rounded once (contract off).
// Strict '<' + ascending m == stable lower-index-first tie-breaking.
// ---------------------------------------------------------------------------
__global__ __launch_bounds__(256) void top2_kernel(
    const float* __restrict__ src_feats, const float* __restrict__ tgt_feats,
    const float* __restrict__ qq_src, const float* __restrict__ qq_tgt,
    float* __restrict__ pd0, float* __restrict__ pd1,
    int* __restrict__ pi0, int* __restrict__ pi1,
    int nch, int chsz)
{
    const int side = blockIdx.z;
    const int ch   = blockIdx.y;
    const int tid  = threadIdx.x;
    const int n    = blockIdx.x * 256 + tid;

    const float* qf = (side == 0) ? src_feats : tgt_feats;
    const float* sf = (side == 0) ? tgt_feats : src_feats;
    const float* qq = (side == 0) ? qq_src    : qq_tgt;
    const float* ss = (side == 0) ? qq_tgt    : qq_src;

    __shared__ float sd[TCAND][CF];    // 16 KiB
    __shared__ float sss[TCAND];       // 256 B

    float qd[CF];
    #pragma unroll
    for (int c = 0; c < CF; c += 4) {
        float4 v = *(const float4*)(qf + (size_t)n * CF + c);
        qd[c] = v.x; qd[c+1] = v.y; qd[c+2] = v.z; qd[c+3] = v.w;
    }
    const float qqn = qq[n];

    float d0 = 3.4e38f, d1 = 3.4e38f;
    int i0 = 0, i1 = 0;

    const int m0 = ch * chsz;
    float* sflat = &sd[0][0];
    for (int t0 = 0; t0 < chsz; t0 += TCAND) {
        __syncthreads();
        const float4* g4 = (const float4*)(sf + (size_t)(m0 + t0) * CF);
        #pragma unroll
        for (int k = 0; k < 4; ++k) {
            int idx = k * 256 + tid;
            float4 v = g4[idx];
            sflat[idx*4+0] = v.x; sflat[idx*4+1] = v.y;
            sflat[idx*4+2] = v.z; sflat[idx*4+3] = v.w;
        }
        if (tid < TCAND) sss[tid] = ss[m0 + t0 + tid];
        __syncthreads();

        #pragma unroll 2
        for (int mm = 0; mm < TCAND; ++mm) {
            const float* s = sd[mm];
            float dot = dot_fma(qd, s);
            float d2;
            {
#pragma clang fp contract(off)
                float twod = 2.0f * dot;          // exact
                float t1v  = qqn - twod;          // one RNE round
                d2 = t1v + sss[mm];               // one RNE round
            }
            int m = m0 + t0 + mm;
            if (d2 < d1) {
                if (d2 < d0) { d1 = d0; i1 = i0; d0 = d2; i0 = m; }
                else         { d1 = d2; i1 = m; }
            }
        }
    }
    size_t slot = ((size_t)side * nch + ch) * NPTS + n;
    pd0[slot] = d0; pd1[slot] = d1;
    pi0[slot] = i0; pi1[slot] = i1;
}

// ---------------------------------------------------------------------------
// merge: combine chunk partials (ascending chunk order, strict '<' keeps the
// lowest index on ties), then sims via the 8-lane-FMA vectorized dot and the
// Lowe-ratio weight in strict fp32.
// ---------------------------------------------------------------------------
__global__ __launch_bounds__(256) void merge_kernel(
    const float* __restrict__ src_feats, const float* __restrict__ tgt_feats,
    const float* __restrict__ pd0, const float* __restrict__ pd1,
    const int* __restrict__ pi0, const int* __restrict__ pi1,
    int nch,
    float* __restrict__ wgt, int* __restrict__ bidx)
{
    int t = blockIdx.x * blockDim.x + threadIdx.x;   // 0 .. 2*NPTS-1
    if (t >= 2 * NPTS) return;
    int side = t >> 14, n = t & (NPTS - 1);

    float d0 = 3.4e38f, d1 = 3.4e38f;
    int i0 = 0, i1 = 0;
    for (int ch = 0; ch < nch; ++ch) {
        size_t slot = ((size_t)side * nch + ch) * NPTS + n;
        float cd0 = pd0[slot], cd1 = pd1[slot];
        int   ci0 = pi0[slot], ci1 = pi1[slot];
        if (cd0 < d1) {
            if (cd0 < d0) { d1 = d0; i1 = i0; d0 = cd0; i0 = ci0; }
            else          { d1 = cd0; i1 = ci0; }
        }
        if (cd1 < d1) {
            if (cd1 < d0) { d1 = d0; i1 = i0; d0 = cd1; i0 = ci1; }
            else          { d1 = cd1; i1 = ci1; }
        }
    }
    if (i0 < 0) i0 = 0;
    if (i1 < 0) i1 = 0;

    const float* qf = (side == 0) ? src_feats : tgt_feats;
    const float* sf = (side == 0) ? tgt_feats : src_feats;

    float q[CF];
    #pragma unroll
    for (int c = 0; c < CF; c += 4) {
        float4 v = *(const float4*)(qf + (size_t)n * CF + c);
        q[c] = v.x; q[c+1] = v.y; q[c+2] = v.z; q[c+3] = v.w;
    }

    float dotA = dot_avx2(sf + (size_t)i0 * CF, q);
    float dotB = dot_avx2(sf + (size_t)i1 * CF, q);

    float w;
    {
#pragma clang fp contract(off)
        float sim0 = 1.0f - dotA;
        float sim1 = 1.0f - dotB;
        float den  = sim1 + 1e-8f;
        w = 1.0f - sim0 / den;
    }
    wgt[t]  = w;
    bidx[t] = i0;
}

// ---------------------------------------------------------------------------
// rank + gather: exact rank of each query's fp32 weight (count strictly
// greater, index tie-break) == position in stable descending top_k order.
// rank < KCORR writes its output row (fp32, exact copies).
// ---------------------------------------------------------------------------
__global__ __launch_bounds__(256) void rank_gather_kernel(
    const float* __restrict__ wgt, const int* __restrict__ bidx,
    const float* __restrict__ src_points, const float* __restrict__ tgt_points,
    const float* __restrict__ src_feats,  const float* __restrict__ tgt_feats,
    float* __restrict__ out)
{
    const int side = blockIdx.y;
    const int n = blockIdx.x * 256 + threadIdx.x;     // 0 .. NPTS-1
    const float* w = wgt + (size_t)side * NPTS;
    const float wn = w[n];

    __shared__ float tile[4096];
    int cnt = 0;
    for (int t0 = 0; t0 < NPTS; t0 += 4096) {
        __syncthreads();
        for (int j = threadIdx.x; j < 4096; j += 256) tile[j] = w[t0 + j];
        __syncthreads();
        #pragma unroll 8
        for (int j = 0; j < 4096; ++j) {
            float wj = tile[j];
            int jj = t0 + j;
            cnt += (wj > wn) || (wj == wn && jj < n);
        }
    }

    if (cnt < KCORR) {
        int r = side * KCORR + cnt;
        int sidx = bidx[(size_t)side * NPTS + n];
        if (sidx < 0) sidx = 0;
        int src_row = (side == 0) ? n : sidx;
        int tgt_row = (side == 0) ? sidx : n;

        float* out_srcP = out;                          // [2K,3]
        float* out_tgtP = out + 2 * KCORR * 3;          // [2K,3]
        float* out_srcF = out + 4 * KCORR * 3;          // [2K,64]
        float* out_tgtF = out_srcF + 2 * KCORR * CF;    // [2K,64]
        float* out_w    = out_tgtF + 2 * KCORR * CF;    // [2K]

        #pragma unroll
        for (int k = 0; k < 3; ++k) {
            out_srcP[(size_t)r * 3 + k] = src_points[(size_t)src_row * 3 + k];
            out_tgtP[(size_t)r * 3 + k] = tgt_points[(size_t)tgt_row * 3 + k];
        }
        const float4* sfr = (const float4*)(src_feats + (size_t)src_row * CF);
        const float4* tfr = (const float4*)(tgt_feats + (size_t)tgt_row * CF);
        float4* so = (float4*)(out_srcF + (size_t)r * CF);
        float4* to = (float4*)(out_tgtF + (size_t)r * CF);
        #pragma unroll
        for (int c = 0; c < CF / 4; ++c) { so[c] = sfr[c]; to[c] = tfr[c]; }
        out_w[r] = wn;
    }
}

// ---------------------------------------------------------------------------
extern "C" void kernel_launch(void* const* d_in, const int* in_sizes, int n_in,
                              void* d_out, int out_size, void* d_ws, size_t ws_size,
                              hipStream_t stream)
{
    const float* src_points = (const float*)d_in[0];
    const float* tgt_points = (const float*)d_in[1];
    const float* src_feats  = (const float*)d_in[2];
    const float* tgt_feats  = (const float*)d_in[3];
    float* out = (float*)d_out;
    (void)in_sizes; (void)n_in; (void)out_size;

    // --- adaptive chunk count so the workspace is guaranteed to fit ---
    auto rup = [](size_t b) { return (b + 255) & ~(size_t)255; };
    size_t base = rup(sizeof(float) * NPTS) * 2         // qq_src, qq_tgt
                + rup(sizeof(float) * 2 * NPTS)         // wgt
                + rup(sizeof(int) * 2 * NPTS);          // bidx
    size_t per_chunk = rup(sizeof(float) * 2 * NPTS) * 2    // pd0, pd1
                     + rup(sizeof(int) * 2 * NPTS) * 2;     // pi0, pi1
    int nch = 16;
    while (nch > 1 && base + (size_t)nch * per_chunk > ws_size) nch >>= 1;
    int chsz = NPTS / nch;
    size_t nslots = (size_t)2 * nch * NPTS;

    char* ws = (char*)d_ws;
    size_t off = 0;
    auto alloc = [&](size_t bytes) -> void* {
        void* p = ws + off;
        off += (bytes + 255) & ~(size_t)255;
        return p;
    };
    float* qq_src = (float*)alloc(sizeof(float) * NPTS);
    float* qq_tgt = (float*)alloc(sizeof(float) * NPTS);
    float* wgt    = (float*)alloc(sizeof(float) * 2 * NPTS);
    int*   bidx   = (int*)alloc(sizeof(int) * 2 * NPTS);
    float* pd0    = (float*)alloc(sizeof(float) * nslots);
    float* pd1    = (float*)alloc(sizeof(float) * nslots);
    int*   pi0    = (int*)alloc(sizeof(int) * nslots);
    int*   pi1    = (int*)alloc(sizeof(int) * nslots);

    prep_kernel<<<(2 * NPTS + 255) / 256, 256, 0, stream>>>(
        src_feats, tgt_feats, qq_src, qq_tgt);

    top2_kernel<<<dim3(NPTS / 256, nch, 2), 256, 0, stream>>>(
        src_feats, tgt_feats, qq_src, qq_tgt,
        pd0, pd1, pi0, pi1, nch, chsz);

    merge_kernel<<<(2 * NPTS + 255) / 256, 256, 0, stream>>>(
        src_feats, tgt_feats, pd0, pd1, pi0, pi1, nch, wgt, bidx);

    rank_gather_kernel<<<dim3(NPTS / 256, 2), 256, 0, stream>>>(
        wgt, bidx, src_points, tgt_points, src_feats, tgt_feats, out);
}

// Round 13
// 1474.590 us; speedup vs baseline: 1.0156x; 1.0156x over previous
//
#include <hip/hip_runtime.h>

#define NPTS 16384
#define CF 64
#define KCORR 2048
#define TCAND 64          // candidates per LDS tile in top2

// ---------------------------------------------------------------------------
// fp32 arithmetic variants (bit-exact emulation targets) -- DO NOT TOUCH.
// dot_avx2: the reference's weight arithmetic (8-lane FMA + halving tree).
// ---------------------------------------------------------------------------
__device__ __forceinline__ float dot_avx2(const float* __restrict__ a,
                                          const float* __restrict__ b) {
#pragma clang fp contract(off)
    float v0 = 0.f, v1 = 0.f, v2 = 0.f, v3 = 0.f;
    float v4 = 0.f, v5 = 0.f, v6 = 0.f, v7 = 0.f;
    #pragma unroll
    for (int i = 0; i < CF; i += 8) {
        v0 = fmaf(a[i + 0], b[i + 0], v0);
        v1 = fmaf(a[i + 1], b[i + 1], v1);
        v2 = fmaf(a[i + 2], b[i + 2], v2);
        v3 = fmaf(a[i + 3], b[i + 3], v3);
        v4 = fmaf(a[i + 4], b[i + 4], v4);
        v5 = fmaf(a[i + 5], b[i + 5], v5);
        v6 = fmaf(a[i + 6], b[i + 6], v6);
        v7 = fmaf(a[i + 7], b[i + 7], v7);
    }
    float u0 = v0 + v4, u1 = v1 + v5, u2 = v2 + v6, u3 = v3 + v7;
    float t0 = u0 + u2, t1 = u1 + u3;
    return t0 + t1;
}

// numpy pairwise_sum (selection-side row norms; same bits as round 12).
__device__ __forceinline__ float row_sumsq(const float* __restrict__ x) {
#pragma clang fp contract(off)
    float r[8];
    #pragma unroll
    for (int j = 0; j < 8; ++j) r[j] = x[j] * x[j];
    #pragma unroll
    for (int i = 8; i < 64; i += 8) {
        #pragma unroll
        for (int j = 0; j < 8; ++j) { float p = x[i + j] * x[i + j]; r[j] = r[j] + p; }
    }
    return ((r[0] + r[1]) + (r[2] + r[3])) + ((r[4] + r[5]) + (r[6] + r[7]));
}

// ---------------------------------------------------------------------------
// prep: per-row sum of squares. One thread per row. (unchanged)
// ---------------------------------------------------------------------------
__global__ __launch_bounds__(256) void prep_kernel(
    const float* __restrict__ src_feats, const float* __restrict__ tgt_feats,
    float* __restrict__ qq_src, float* __restrict__ qq_tgt)
{
    int t = blockIdx.x * 256 + threadIdx.x;      // 0 .. 2*NPTS-1
    if (t >= 2 * NPTS) return;
    const float* f = (t < NPTS) ? src_feats : tgt_feats;
    float*      qq = (t < NPTS) ? qq_src    : qq_tgt;
    int n = (t < NPTS) ? t : t - NPTS;
    float x[CF];
    #pragma unroll
    for (int c = 0; c < CF; c += 4) {
        float4 v = *(const float4*)(f + (size_t)n * CF + c);
        x[c] = v.x; x[c+1] = v.y; x[c+2] = v.z; x[c+3] = v.w;
    }
    qq[n] = row_sumsq(x);
}

// ---------------------------------------------------------------------------
// top2 v2: query row pinned in VGPRs (float4 qv[16], fully unrolled,
// launch_bounds(256,2) lifts the VGPR cap so the compiler keeps it resident
// instead of re-fetching from global per candidate -- round 12's 35.5 GB
// FETCH_SIZE / 52-VGPR pathology).
// FMA chain order IDENTICAL to round 12 (ascending c, acc=fmaf(q,s,acc)),
// d2 = (qq - 2*dot) + ss with one rounding per step, strict '<' ties.
// ---------------------------------------------------------------------------
__global__ __launch_bounds__(256, 2) void top2_kernel(
    const float* __restrict__ src_feats, const float* __restrict__ tgt_feats,
    const float* __restrict__ qq_src, const float* __restrict__ qq_tgt,
    float* __restrict__ pd0, float* __restrict__ pd1,
    int* __restrict__ pi0, int* __restrict__ pi1,
    int nch, int chsz)
{
    const int side = blockIdx.z;
    const int ch   = blockIdx.y;
    const int tid  = threadIdx.x;
    const int n    = blockIdx.x * 256 + tid;

    const float* qf = (side == 0) ? src_feats : tgt_feats;
    const float* sf = (side == 0) ? tgt_feats : src_feats;
    const float* qq = (side == 0) ? qq_src    : qq_tgt;
    const float* ss = (side == 0) ? qq_tgt    : qq_src;

    __shared__ float sd[TCAND][CF];    // 16 KiB
    __shared__ float sss[TCAND];       // 256 B

    // query row resident in 64 VGPRs
    float4 qv[16];
    {
        const float4* q4 = (const float4*)(qf + (size_t)n * CF);
        #pragma unroll
        for (int g = 0; g < 16; ++g) qv[g] = q4[g];
    }
    const float qqn = qq[n];

    float d0 = 3.4e38f, d1 = 3.4e38f;
    int i0 = 0, i1 = 0;

    const int m0 = ch * chsz;
    float* sflat = &sd[0][0];
    for (int t0 = 0; t0 < chsz; t0 += TCAND) {
        __syncthreads();
        const float4* g4 = (const float4*)(sf + (size_t)(m0 + t0) * CF);
        #pragma unroll
        for (int k = 0; k < 4; ++k) {
            int idx = k * 256 + tid;
            float4 v = g4[idx];
            sflat[idx*4+0] = v.x; sflat[idx*4+1] = v.y;
            sflat[idx*4+2] = v.z; sflat[idx*4+3] = v.w;
        }
        if (tid < TCAND) sss[tid] = ss[m0 + t0 + tid];
        __syncthreads();

        for (int mm = 0; mm < TCAND; ++mm) {
            const float4* s4 = (const float4*)sd[mm];
            float acc = 0.0f;
            #pragma unroll
            for (int g = 0; g < 16; ++g) {
                float4 sv = s4[g];
                acc = fmaf(qv[g].x, sv.x, acc);
                acc = fmaf(qv[g].y, sv.y, acc);
                acc = fmaf(qv[g].z, sv.z, acc);
                acc = fmaf(qv[g].w, sv.w, acc);
            }
            float d2;
            {
#pragma clang fp contract(off)
                float twod = 2.0f * acc;          // exact
                float t1v  = qqn - twod;          // one RNE round
                d2 = t1v + sss[mm];               // one RNE round
            }
            int m = m0 + t0 + mm;
            if (d2 < d1) {
                if (d2 < d0) { d1 = d0; i1 = i0; d0 = d2; i0 = m; }
                else         { d1 = d2; i1 = m; }
            }
        }
    }
    size_t slot = ((size_t)side * nch + ch) * NPTS + n;
    pd0[slot] = d0; pd1[slot] = d1;
    pi0[slot] = i0; pi1[slot] = i1;
}

// ---------------------------------------------------------------------------
// merge: combine chunk partials, sims via dot_avx2, weight in strict fp32.
// (unchanged from the passing round)
// ---------------------------------------------------------------------------
__global__ __launch_bounds__(256) void merge_kernel(
    const float* __restrict__ src_feats, const float* __restrict__ tgt_feats,
    const float* __restrict__ pd0, const float* __restrict__ pd1,
    const int* __restrict__ pi0, const int* __restrict__ pi1,
    int nch,
    float* __restrict__ wgt, int* __restrict__ bidx)
{
    int t = blockIdx.x * blockDim.x + threadIdx.x;   // 0 .. 2*NPTS-1
    if (t >= 2 * NPTS) return;
    int side = t >> 14, n = t & (NPTS - 1);

    float d0 = 3.4e38f, d1 = 3.4e38f;
    int i0 = 0, i1 = 0;
    for (int ch = 0; ch < nch; ++ch) {
        size_t slot = ((size_t)side * nch + ch) * NPTS + n;
        float cd0 = pd0[slot], cd1 = pd1[slot];
        int   ci0 = pi0[slot], ci1 = pi1[slot];
        if (cd0 < d1) {
            if (cd0 < d0) { d1 = d0; i1 = i0; d0 = cd0; i0 = ci0; }
            else          { d1 = cd0; i1 = ci0; }
        }
        if (cd1 < d1) {
            if (cd1 < d0) { d1 = d0; i1 = i0; d0 = cd1; i0 = ci1; }
            else          { d1 = cd1; i1 = ci1; }
        }
    }
    if (i0 < 0) i0 = 0;
    if (i1 < 0) i1 = 0;

    const float* qf = (side == 0) ? src_feats : tgt_feats;
    const float* sf = (side == 0) ? tgt_feats : src_feats;

    float q[CF];
    #pragma unroll
    for (int c = 0; c < CF; c += 4) {
        float4 v = *(const float4*)(qf + (size_t)n * CF + c);
        q[c] = v.x; q[c+1] = v.y; q[c+2] = v.z; q[c+3] = v.w;
    }

    float dotA = dot_avx2(sf + (size_t)i0 * CF, q);
    float dotB = dot_avx2(sf + (size_t)i1 * CF, q);

    float w;
    {
#pragma clang fp contract(off)
        float sim0 = 1.0f - dotA;
        float sim1 = 1.0f - dotB;
        float den  = sim1 + 1e-8f;
        w = 1.0f - sim0 / den;
    }
    wgt[t]  = w;
    bidx[t] = i0;
}

// ---------------------------------------------------------------------------
// rank + gather (unchanged from the passing round)
// ---------------------------------------------------------------------------
__global__ __launch_bounds__(256) void rank_gather_kernel(
    const float* __restrict__ wgt, const int* __restrict__ bidx,
    const float* __restrict__ src_points, const float* __restrict__ tgt_points,
    const float* __restrict__ src_feats,  const float* __restrict__ tgt_feats,
    float* __restrict__ out)
{
    const int side = blockIdx.y;
    const int n = blockIdx.x * 256 + threadIdx.x;     // 0 .. NPTS-1
    const float* w = wgt + (size_t)side * NPTS;
    const float wn = w[n];

    __shared__ float tile[4096];
    int cnt = 0;
    for (int t0 = 0; t0 < NPTS; t0 += 4096) {
        __syncthreads();
        for (int j = threadIdx.x; j < 4096; j += 256) tile[j] = w[t0 + j];
        __syncthreads();
        #pragma unroll 8
        for (int j = 0; j < 4096; ++j) {
            float wj = tile[j];
            int jj = t0 + j;
            cnt += (wj > wn) || (wj == wn && jj < n);
        }
    }

    if (cnt < KCORR) {
        int r = side * KCORR + cnt;
        int sidx = bidx[(size_t)side * NPTS + n];
        if (sidx < 0) sidx = 0;
        int src_row = (side == 0) ? n : sidx;
        int tgt_row = (side == 0) ? sidx : n;

        float* out_srcP = out;                          // [2K,3]
        float* out_tgtP = out + 2 * KCORR * 3;          // [2K,3]
        float* out_srcF = out + 4 * KCORR * 3;          // [2K,64]
        float* out_tgtF = out_srcF + 2 * KCORR * CF;    // [2K,64]
        float* out_w    = out_tgtF + 2 * KCORR * CF;    // [2K]

        #pragma unroll
        for (int k = 0; k < 3; ++k) {
            out_srcP[(size_t)r * 3 + k] = src_points[(size_t)src_row * 3 + k];
            out_tgtP[(size_t)r * 3 + k] = tgt_points[(size_t)tgt_row * 3 + k];
        }
        const float4* sfr = (const float4*)(src_feats + (size_t)src_row * CF);
        const float4* tfr = (const float4*)(tgt_feats + (size_t)tgt_row * CF);
        float4* so = (float4*)(out_srcF + (size_t)r * CF);
        float4* to = (float4*)(out_tgtF + (size_t)r * CF);
        #pragma unroll
        for (int c = 0; c < CF / 4; ++c) { so[c] = sfr[c]; to[c] = tfr[c]; }
        out_w[r] = wn;
    }
}

// ---------------------------------------------------------------------------
extern "C" void kernel_launch(void* const* d_in, const int* in_sizes, int n_in,
                              void* d_out, int out_size, void* d_ws, size_t ws_size,
                              hipStream_t stream)
{
    const float* src_points = (const float*)d_in[0];
    const float* tgt_points = (const float*)d_in[1];
    const float* src_feats  = (const float*)d_in[2];
    const float* tgt_feats  = (const float*)d_in[3];
    float* out = (float*)d_out;
    (void)in_sizes; (void)n_in; (void)out_size;

    // --- adaptive chunk count so the workspace is guaranteed to fit ---
    auto rup = [](size_t b) { return (b + 255) & ~(size_t)255; };
    size_t base = rup(sizeof(float) * NPTS) * 2         // qq_src, qq_tgt
                + rup(sizeof(float) * 2 * NPTS)         // wgt
                + rup(sizeof(int) * 2 * NPTS);          // bidx
    size_t per_chunk = rup(sizeof(float) * 2 * NPTS) * 2    // pd0, pd1
                     + rup(sizeof(int) * 2 * NPTS) * 2;     // pi0, pi1
    int nch = 16;
    while (nch > 1 && base + (size_t)nch * per_chunk > ws_size) nch >>= 1;
    int chsz = NPTS / nch;
    size_t nslots = (size_t)2 * nch * NPTS;

    char* ws = (char*)d_ws;
    size_t off = 0;
    auto alloc = [&](size_t bytes) -> void* {
        void* p = ws + off;
        off += (bytes + 255) & ~(size_t)255;
        return p;
    };
    float* qq_src = (float*)alloc(sizeof(float) * NPTS);
    float* qq_tgt = (float*)alloc(sizeof(float) * NPTS);
    float* wgt    = (float*)alloc(sizeof(float) * 2 * NPTS);
    int*   bidx   = (int*)alloc(sizeof(int) * 2 * NPTS);
    float* pd0    = (float*)alloc(sizeof(float) * nslots);
    float* pd1    = (float*)alloc(sizeof(float) * nslots);
    int*   pi0    = (int*)alloc(sizeof(int) * nslots);
    int*   pi1    = (int*)alloc(sizeof(int) * nslots);

    prep_kernel<<<(2 * NPTS + 255) / 256, 256, 0, stream>>>(
        src_feats, tgt_feats, qq_src, qq_tgt);

    top2_kernel<<<dim3(NPTS / 256, nch, 2), 256, 0, stream>>>(
        src_feats, tgt_feats, qq_src, qq_tgt,
        pd0, pd1, pi0, pi1, nch, chsz);

    merge_kernel<<<(2 * NPTS + 255) / 256, 256, 0, stream>>>(
        src_feats, tgt_feats, pd0, pd1, pi0, pi1, nch, wgt, bidx);

    rank_gather_kernel<<<dim3(NPTS / 256, 2), 256, 0, stream>>>(
        wgt, bidx, src_points, tgt_points, src_feats, tgt_feats, out);
}